// Round 17
// baseline (88.249 us; speedup 1.0000x reference)
//
#include <hip/hip_runtime.h>

#define N_NODES 50000
#define F_IN    512
#define F_OUT   96
#define N_EDGES 800000

#define RPB    128                          // rows per coarse bucket
#define NBKT   391                          // ceil(50000/128)
#define CAP    2560                         // bucket capacity (mean 2048, +11 sigma)
#define ECHUNK 4096
#define NCHUNK ((N_EDGES + ECHUNK - 1) / ECHUNK)   // 196 fill blocks
#define WCB    96                                  // wcast blocks (512 thr)
#define GEMM_BLOCKS ((N_NODES + 63) / 64)          // 782 (64 rows per block)

typedef __attribute__((ext_vector_type(8))) short bf16x8;
typedef __attribute__((ext_vector_type(4))) float f32x4;

// f32 -> bf16 round-to-nearest-even (bit pattern)
__device__ __forceinline__ unsigned short f2bf(float f) {
    unsigned int u = __float_as_uint(f);
    unsigned int r = (u + 0x7FFFu + ((u >> 16) & 1u)) >> 16;
    return (unsigned short)r;
}
__device__ __forceinline__ float bf2f(unsigned short h) {
    return __uint_as_float(((unsigned int)h) << 16);
}

// ---------------------------------------------------------------------------
// Zero bcnt (must complete before fill's reservations)
// ---------------------------------------------------------------------------
__global__ __launch_bounds__(512) void k_zero(int* __restrict__ bcnt) {
    if (threadIdx.x < 400) bcnt[threadIdx.x] = 0;
}

// ---------------------------------------------------------------------------
// FILL + WCAST in one dispatch (independent of each other; both feed later
// dispatches). Blocks [0,NCHUNK) = edge multisplit fill; [NCHUNK,NCHUNK+WCB)
// = weight cast to fragment-major wTq.
// ---------------------------------------------------------------------------
__global__ __launch_bounds__(512) void k_fillwcast(const int* __restrict__ erow,
                                                   const int* __restrict__ ecol,
                                                   const float* __restrict__ eval,
                                                   int* __restrict__ bcnt,
                                                   float2* __restrict__ bucket,
                                                   const float* __restrict__ w,
                                                   unsigned short* __restrict__ wTq) {
    __shared__ int smem[1200];
    const int tid = threadIdx.x;

    if (blockIdx.x >= NCHUNK) {
        // ---------------- wcast path ----------------
        const int i = (blockIdx.x - NCHUNK) * 512 + tid;   // 0..49151
        if (i < F_OUT * F_IN) {
            const int j    = i & 7;
            const int lane = (i >> 3) & 63;
            const int ks   = (i >> 9) & 1;
            const int tp   = i >> 10;          // 0..47
            const int t    = tp % 6;
            const int p    = tp / 6;
            const int lr   = lane & 15;
            const int kg   = lane >> 4;
            const int n    = t * 16 + lr;
            const int k    = p * 64 + ks * 32 + kg * 8 + j;
            wTq[i] = f2bf(w[(size_t)k * F_OUT + n]);
        }
        return;
    }

    // ---------------- fill path ----------------
    int* hist  = smem;                // [NBKT]
    int* gbase = smem + 400;          // [NBKT]
    int* lcur  = smem + 800;          // [NBKT]
    for (int i = tid; i < NBKT; i += 512) { hist[i] = 0; lcur[i] = 0; }
    __syncthreads();

    const int base = blockIdx.x * ECHUNK;
    const int n = min(ECHUNK, N_EDGES - base);

    for (int i = tid; i < n; i += 512)
        atomicAdd(&hist[erow[base + i] >> 7], 1);
    __syncthreads();

    for (int b = tid; b < NBKT; b += 512)
        gbase[b] = hist[b] ? atomicAdd(&bcnt[b], hist[b]) : 0;
    __syncthreads();

    for (int i = tid; i < n; i += 512) {
        const int r = erow[base + i];
        const int b = r >> 7;
        const int pos = gbase[b] + atomicAdd(&lcur[b], 1);
        if (pos >= 0 && pos < CAP)
            bucket[(size_t)b * CAP + pos] = make_float2(
                __int_as_float(((r & 127) << 16) | ecol[base + i]),
                eval[base + i]);
    }
}

// ---------------------------------------------------------------------------
// GEMM solo (R15 structure verbatim): 512 threads, 8 waves; wave = 16 rows x
// 48 cols (wr=wave&3, wc=wave>>2). A staged in 2 x 8 KB LDS (bf16, swizzled,
// reg-staged issue-early/write-late); B per-MFMA coalesced 1 KB loads from
// L2-resident wTq. This round: SOLO DISPATCH for timing attribution.
// ---------------------------------------------------------------------------
__global__ __launch_bounds__(512) void k_gemm(const float* __restrict__ x,
                                              const unsigned short* __restrict__ wTq,
                                              unsigned short* __restrict__ support) {
    __shared__ __align__(16) char smem[16384];   // 2 x 8 KB A tiles
    const int tid = threadIdx.x;

    unsigned short (*sX)[64 * 64] = (unsigned short (*)[64 * 64])smem;

    const int lane = tid & 63;
    const int wave = tid >> 6;         // 0..7
    const int wr   = wave & 3;         // row group (16 rows)
    const int wc   = wave >> 2;        // col group (48 cols)
    const int r0   = blockIdx.x * 64;
    const int lr   = lane & 15;
    const int kg   = lane >> 4;

    f32x4 acc[3];
    #pragma unroll
    for (int t = 0; t < 3; ++t) acc[t] = (f32x4){0.f, 0.f, 0.f, 0.f};

    float4 xr[2];   // A staging: 1024 chunks / 512 threads = 2 each

    auto XLOAD = [&](int p) {
        #pragma unroll
        for (int i = 0; i < 2; ++i) {
            const int chunk = i * 512 + tid;       // 0..1023
            const int row   = chunk >> 4;          // 0..63
            const int c     = chunk & 15;          // float4 index in row
            int gr = r0 + row;
            if (gr > N_NODES - 1) gr = N_NODES - 1;   // clamp: dup row, store-masked
            xr[i] = *reinterpret_cast<const float4*>(x + (size_t)gr * F_IN + p * 64 + c * 4);
        }
    };
    auto XWRITE = [&](int buf) {
        char* xb = (char*)&sX[buf][0];
        #pragma unroll
        for (int i = 0; i < 2; ++i) {
            const int chunk = i * 512 + tid;
            const int row   = chunk >> 4;
            const int c     = chunk & 15;
            ushort4 h;
            h.x = f2bf(xr[i].x); h.y = f2bf(xr[i].y);
            h.z = f2bf(xr[i].z); h.w = f2bf(xr[i].w);
            const int byte = (c * 8) ^ ((row & 7) << 4);
            *reinterpret_cast<ushort4*>(xb + row * 128 + byte) = h;
        }
    };
    auto COMPUTE = [&](int buf, int p) {
        const char* xb = (const char*)&sX[buf][0];
        const int xrow = wr * 16 + lr;
        const unsigned short* bbase = wTq + ((size_t)p * 12 + wc * 6) * 512 + lane * 8;
        #pragma unroll
        for (int ks = 0; ks < 2; ++ks) {
            const int off = (ks * 64 + kg * 16) ^ ((xrow & 7) << 4);
            const bf16x8 af = *reinterpret_cast<const bf16x8*>(xb + xrow * 128 + off);
            #pragma unroll
            for (int t = 0; t < 3; ++t) {
                const bf16x8 bq = *reinterpret_cast<const bf16x8*>(
                    bbase + (t * 2 + ks) * 512);
                acc[t] = __builtin_amdgcn_mfma_f32_16x16x32_bf16(af, bq, acc[t], 0, 0, 0);
            }
        }
    };

    XLOAD(0);
    XWRITE(0);
    __syncthreads();
    for (int p = 0; p < 8; ++p) {
        if (p < 7) XLOAD(p + 1);        // issue next panel's loads early
        COMPUTE(p & 1, p);              // MFMAs + coalesced B loads
        if (p < 7) XWRITE((p + 1) & 1); // write late (T14)
        __syncthreads();                // one barrier per panel
    }

    // ---- store (bf16): col = wc*48 + t*16 + lr, row = wr*16 + kg*4 + r ----
    #pragma unroll
    for (int t = 0; t < 3; ++t) {
        #pragma unroll
        for (int r = 0; r < 4; ++r) {
            const int row = r0 + wr * 16 + kg * 4 + r;
            if (row < N_NODES)
                support[(size_t)row * F_OUT + wc * 48 + t * 16 + lr] = f2bf(acc[t][r]);
        }
    }
}

// ---------------------------------------------------------------------------
// S: in-bucket row sort -> bucket2 (fixed-cap layout) + per-row offsets.
// rowOffs layout: [b*129 + 0..127] = row bases, [b*129 + 128] = bucket end.
// ---------------------------------------------------------------------------
__global__ __launch_bounds__(256) void kS_sort(const int* __restrict__ bcnt,
                                               const float2* __restrict__ bucket,
                                               float2* __restrict__ bucket2,
                                               int* __restrict__ rowOffs) {
    __shared__ int cnt[RPB];
    __shared__ int sc[RPB];
    __shared__ int rbase[RPB];
    __shared__ int rcur[RPB];
    const int b   = blockIdx.x;
    const int tid = threadIdx.x;

    if (tid < RPB) { cnt[tid] = 0; rcur[tid] = 0; }
    __syncthreads();

    const int beg = b * CAP;
    const int n   = min(bcnt[b], CAP);

    for (int i = tid; i < n; i += 256)
        atomicAdd(&cnt[(__float_as_int(bucket[beg + i].x) >> 16) & 127], 1);
    __syncthreads();

    if (tid < RPB) sc[tid] = cnt[tid];
    __syncthreads();
    #pragma unroll
    for (int off = 1; off < RPB; off <<= 1) {
        int a = 0;
        if (tid < RPB && tid >= off) a = sc[tid - off];
        __syncthreads();
        if (tid < RPB) sc[tid] += a;
        __syncthreads();
    }
    if (tid < RPB) {
        const int rb = beg + sc[tid] - cnt[tid];   // exclusive
        rbase[tid] = rb;
        rowOffs[b * 129 + tid] = rb;
    }
    if (tid == RPB) rowOffs[b * 129 + RPB] = beg + n;
    __syncthreads();

    for (int i = tid; i < n; i += 256) {
        const float2 ev  = bucket[beg + i];
        const int    key = __float_as_int(ev.x);
        const int    r   = (key >> 16) & 127;
        const int    pos = rbase[r] + atomicAdd(&rcur[r], 1);
        bucket2[pos] = make_float2(__int_as_float(key & 0xFFFF), ev.y);
    }
}

// ---------------------------------------------------------------------------
// Gather: thread = (row, f16), f16 in [0,6) -> 16 features. bf16 support.
// Register accumulate, fused ReLU, single write. No atomics.
// ---------------------------------------------------------------------------
__global__ __launch_bounds__(256) void k_gather(const int* __restrict__ rowOffs,
                                                const float2* __restrict__ bucket2,
                                                const unsigned short* __restrict__ support,
                                                float* __restrict__ out) {
    const int gid = blockIdx.x * 256 + threadIdx.x;
    if (gid >= N_NODES * 6) return;
    const int r   = gid / 6;
    const int f16 = gid - r * 6;

    const int idx = (r >> 7) * 129 + (r & 127);
    const int beg = rowOffs[idx];
    const int end = rowOffs[idx + 1];

    float acc[16];
    #pragma unroll
    for (int j = 0; j < 16; ++j) acc[j] = 0.f;

    for (int i = beg; i < end; ++i) {
        const float2 cv = bucket2[i];
        const int   c = __float_as_int(cv.x);
        const float v = cv.y;
        const unsigned short* sp = support + (size_t)c * F_OUT + f16 * 16;
        const bf16x8 s0 = *reinterpret_cast<const bf16x8*>(sp);
        const bf16x8 s1 = *reinterpret_cast<const bf16x8*>(sp + 8);
        #pragma unroll
        for (int j = 0; j < 8; ++j) {
            acc[j]     = fmaf(v, bf2f((unsigned short)s0[j]), acc[j]);
            acc[8 + j] = fmaf(v, bf2f((unsigned short)s1[j]), acc[8 + j]);
        }
    }

    float* o = out + (size_t)r * F_OUT + f16 * 16;
    #pragma unroll
    for (int q = 0; q < 4; ++q) {
        float4 ov;
        ov.x = fmaxf(acc[q * 4 + 0], 0.f);
        ov.y = fmaxf(acc[q * 4 + 1], 0.f);
        ov.z = fmaxf(acc[q * 4 + 2], 0.f);
        ov.w = fmaxf(acc[q * 4 + 3], 0.f);
        *reinterpret_cast<float4*>(o + q * 4) = ov;
    }
}

extern "C" void kernel_launch(void* const* d_in, const int* in_sizes, int n_in,
                              void* d_out, int out_size, void* d_ws, size_t ws_size,
                              hipStream_t stream) {
    const float* x    = (const float*)d_in[0];
    const int*   erow = (const int*)d_in[1];
    const int*   ecol = (const int*)d_in[2];
    const float* eval = (const float*)d_in[3];
    const float* w    = (const float*)d_in[4];
    float*       out  = (float*)d_out;

    // workspace layout (bytes from d_ws):
    unsigned short* support = (unsigned short*)d_ws;               // 9.6 MB
    int*    bcnt    = (int*)((char*)d_ws + 9600000);               // [391] pad 400
    int*    rowOffs = bcnt + 400;                                  // [50439] pad 50560
    unsigned short* wTq = (unsigned short*)(rowOffs + 50560);      // 49152 bf16
    float2* bucket  = (float2*)((char*)wTq + 98304);               // 8.0 MB
    float2* bucket2 = bucket + (size_t)NBKT * CAP;                 // 8.0 MB

    k_zero<<<1, 512, 0, stream>>>(bcnt);

    k_fillwcast<<<NCHUNK + WCB, 512, 0, stream>>>(erow, ecol, eval,
                                                  bcnt, bucket, w, wTq);

    k_gemm<<<GEMM_BLOCKS, 512, 0, stream>>>(x, wTq, support);

    kS_sort<<<NBKT, 256, 0, stream>>>(bcnt, bucket, bucket2, rowOffs);

    const int gthreads = N_NODES * 6;
    k_gather<<<(gthreads + 255) / 256, 256, 0, stream>>>(rowOffs, bucket2, support, out);
}

// Round 18
// 83.116 us; speedup vs baseline: 1.0618x; 1.0618x over previous
//
#include <hip/hip_runtime.h>

#define N_NODES 50000
#define F_IN    512
#define F_OUT   96
#define N_EDGES 800000

#define RPB    128                          // rows per coarse bucket
#define NBKT   391                          // ceil(50000/128)
#define CAP    2560                         // bucket capacity (mean 2048, +11 sigma)
#define ECHUNK 4096
#define NCHUNK ((N_EDGES + ECHUNK - 1) / ECHUNK)   // 196
#define GEMM_BLOCKS ((N_NODES + 63) / 64)          // 782

typedef __attribute__((ext_vector_type(8))) short bf16x8;
typedef __attribute__((ext_vector_type(4))) float f32x4;

typedef const __attribute__((address_space(1))) void* gas_ptr;
typedef __attribute__((address_space(3))) void* las_ptr;

__device__ __forceinline__ void gload_lds16(const void* g, void* l) {
    __builtin_amdgcn_global_load_lds((gas_ptr)g, (las_ptr)l, 16, 0, 0);
}

// counted wait + scheduler fence (rule #18). Literal immediate required.
#define VMCNT_SB(n) do { \
    asm volatile("s_waitcnt vmcnt(" #n ")" ::: "memory"); \
    __builtin_amdgcn_sched_barrier(0); \
} while (0)

// f32 -> bf16 round-to-nearest-even (bit pattern)
__device__ __forceinline__ unsigned short f2bf(float f) {
    unsigned int u = __float_as_uint(f);
    unsigned int r = (u + 0x7FFFu + ((u >> 16) & 1u)) >> 16;
    return (unsigned short)r;
}
__device__ __forceinline__ float bf2f(unsigned short h) {
    return __uint_as_float(((unsigned int)h) << 16);
}

// ---------------------------------------------------------------------------
// Weight cast (+ fused bcnt-zero): w[512][96] f32 -> wTq fragment-major bf16:
// i = ((((p*6+t)*2+ks)*64 + lane)*8 + j); value = w[k][n], n = t*16+(lane&15),
// k = p*64+ks*32+(lane>>4)*8+j. A wave's B-fragment = ONE coalesced 1 KB load.
// ---------------------------------------------------------------------------
__global__ __launch_bounds__(256) void k_wcast(const float* __restrict__ w,
                                               unsigned short* __restrict__ wTq,
                                               int* __restrict__ bcnt) {
    if (blockIdx.x == 0) {
        const int t = threadIdx.x;
        bcnt[t] = 0;                       // 0..255
        if (t < 144) bcnt[256 + t] = 0;    // 256..399
    }
    const int i = blockIdx.x * 256 + threadIdx.x;
    if (i < F_OUT * F_IN) {
        const int j    = i & 7;
        const int lane = (i >> 3) & 63;
        const int ks   = (i >> 9) & 1;
        const int tp   = i >> 10;          // 0..47
        const int t    = tp % 6;
        const int p    = tp / 6;
        const int lr   = lane & 15;
        const int kg   = lane >> 4;
        const int n    = t * 16 + lr;
        const int k    = p * 64 + ks * 32 + kg * 8 + j;
        wTq[i] = f2bf(w[(size_t)k * F_OUT + n]);
    }
}

// ---------------------------------------------------------------------------
// FUSED: blocks [0,NCHUNK) = edge multisplit fill; rest = MFMA GEMM.
// GEMM v8 (T3/T4 proper): X f32 staged via gload_lds (NO VGPR cost -> nothing
// to spill) into a 3-slot ring (48 KB); per panel: STAGE(p+2) -> vmcnt(8) ->
// raw s_barrier -> COMPUTE -> raw s_barrier. 8 load-instrs/wave remain in
// flight across EVERY barrier (counted, never 0 until tail) — removes the
// vmcnt(0)-drain that capped R5/R10. B per-MFMA from L2-resident wTq.
// Ledger/wave: G(p) = 4 instrs. Steady outstanding at wait = G(p+1)+G(p+2)=8.
// B loads issue+retire within COMPUTE (compiler counted waits), so the
// static ledger holds: vm 8,8,8,8,8,8,4,0.
// ---------------------------------------------------------------------------
__global__ __launch_bounds__(256) void k_fused(const float* __restrict__ x,
                                               const unsigned short* __restrict__ wTq,
                                               unsigned short* __restrict__ support,
                                               const int* __restrict__ erow,
                                               const int* __restrict__ ecol,
                                               const float* __restrict__ eval,
                                               int* __restrict__ bcnt,
                                               float2* __restrict__ bucket) {
    __shared__ __align__(16) char smem[49152];   // GEMM: 3 x 16 KB X slots
    const int tid = threadIdx.x;

    if (blockIdx.x < NCHUNK) {
        // ---------------- fill path (4.8 KB of smem) ----------------
        int* hist  = (int*)smem;          // [NBKT]
        int* gbase = hist + 400;          // [NBKT]
        int* lcur  = gbase + 400;         // [NBKT]
        for (int i = tid; i < NBKT; i += 256) { hist[i] = 0; lcur[i] = 0; }
        __syncthreads();

        const int base = blockIdx.x * ECHUNK;
        const int n = min(ECHUNK, N_EDGES - base);

        for (int i = tid; i < n; i += 256)
            atomicAdd(&hist[erow[base + i] >> 7], 1);
        __syncthreads();

        for (int b = tid; b < NBKT; b += 256)
            gbase[b] = hist[b] ? atomicAdd(&bcnt[b], hist[b]) : 0;
        __syncthreads();

        for (int i = tid; i < n; i += 256) {
            const int r = erow[base + i];
            const int b = r >> 7;
            const int pos = gbase[b] + atomicAdd(&lcur[b], 1);
            if (pos >= 0 && pos < CAP)
                bucket[(size_t)b * CAP + pos] = make_float2(
                    __int_as_float(((r & 127) << 16) | ecol[base + i]),
                    eval[base + i]);
        }
        return;
    }

    // ---------------- GEMM path ----------------
    const int lane = tid & 63;
    const int wave = tid >> 6;         // 0..3 (wave owns rows wave*16..+15)
    const int r0   = (blockIdx.x - NCHUNK) * 64;
    const int lr   = lane & 15;        // A-row (in wave tile) / B-col / C-col
    const int kg   = lane >> 4;        // k-group 0..3

    f32x4 acc[6];
    #pragma unroll
    for (int t = 0; t < 6; ++t) acc[t] = (f32x4){0.f, 0.f, 0.f, 0.f};

    // stage panel p (f32, 16 KB) into slot s; source pre-XOR-swizzled (R5,
    // verified): linear LDS dest, srcb = (s16*16) ^ ((row&15)<<4).
    auto STAGE = [&](int s, int p) {
        float* dst = (float*)(smem + s * 16384);
        #pragma unroll
        for (int i = 0; i < 4; ++i) {
            const int chunk = i * 256 + tid;           // 0..1023
            const int row   = chunk >> 4;              // 0..63
            const int s16   = chunk & 15;              // 16B slot in row
            int gr = r0 + row;
            if (gr > N_NODES - 1) gr = N_NODES - 1;    // clamp: dup row, store-masked
            const int srcb = (s16 * 16) ^ ((row & 15) << 4);
            gload_lds16(x + (size_t)gr * F_IN + p * 64 + (srcb >> 2),
                        dst + chunk * 4);
        }
    };
    auto COMPUTE = [&](int s, int p) {
        const float* xb = (const float*)(smem + s * 16384);
        const int xrow = wave * 16 + lr;               // xrow&15 == lr
        const unsigned short* bbase = wTq + (size_t)p * 12 * 512 + lane * 8;
        #pragma unroll
        for (int ks = 0; ks < 2; ++ks) {
            const int byte0 = ks * 128 + kg * 32;
            const int b0 = byte0        ^ (lr << 4);
            const int b1 = (byte0 + 16) ^ (lr << 4);
            const float4 a0 = *reinterpret_cast<const float4*>(xb + xrow * 64 + (b0 >> 2));
            const float4 a1 = *reinterpret_cast<const float4*>(xb + xrow * 64 + (b1 >> 2));
            bf16x8 af;
            af[0] = (short)f2bf(a0.x); af[1] = (short)f2bf(a0.y);
            af[2] = (short)f2bf(a0.z); af[3] = (short)f2bf(a0.w);
            af[4] = (short)f2bf(a1.x); af[5] = (short)f2bf(a1.y);
            af[6] = (short)f2bf(a1.z); af[7] = (short)f2bf(a1.w);
            #pragma unroll
            for (int t = 0; t < 6; ++t) {
                const bf16x8 bq = *reinterpret_cast<const bf16x8*>(
                    bbase + (t * 2 + ks) * 512);
                acc[t] = __builtin_amdgcn_mfma_f32_16x16x32_bf16(af, bq, acc[t], 0, 0, 0);
            }
        }
    };

    // prologue: 2 panels in flight
    STAGE(0, 0);
    STAGE(1, 1);                                    // out = 8

    // PANEL(p): stage p+2, wait panel p (counted), barrier, compute, barrier.
    // Trailing barrier also protects slot reuse: STAGE at p+1 overwrites
    // slot (p+3)%3 == p%3, which all waves finished reading at that barrier.
#define PANEL(p, vm) \
    do { \
        if ((p) + 2 < 8) STAGE(((p) + 2) % 3, (p) + 2); \
        VMCNT_SB(vm); \
        __builtin_amdgcn_s_barrier(); \
        COMPUTE((p) % 3, (p)); \
        __builtin_amdgcn_s_barrier(); \
    } while (0)

    PANEL(0, 8);
    PANEL(1, 8);
    PANEL(2, 8);
    PANEL(3, 8);
    PANEL(4, 8);
    PANEL(5, 8);
    PANEL(6, 4);
    PANEL(7, 0);
#undef PANEL

    // ---- store (bf16): C col = lr, row = kg*4 + r ----
    #pragma unroll
    for (int t = 0; t < 6; ++t) {
        #pragma unroll
        for (int r = 0; r < 4; ++r) {
            const int row = r0 + wave * 16 + kg * 4 + r;
            if (row < N_NODES)
                support[(size_t)row * F_OUT + t * 16 + lr] = f2bf(acc[t][r]);
        }
    }
}

// ---------------------------------------------------------------------------
// S: in-bucket row sort -> bucket2 (fixed-cap layout) + per-row offsets.
// rowOffs layout: [b*129 + 0..127] = row bases, [b*129 + 128] = bucket end.
// ---------------------------------------------------------------------------
__global__ __launch_bounds__(256) void kS_sort(const int* __restrict__ bcnt,
                                               const float2* __restrict__ bucket,
                                               float2* __restrict__ bucket2,
                                               int* __restrict__ rowOffs) {
    __shared__ int cnt[RPB];
    __shared__ int sc[RPB];
    __shared__ int rbase[RPB];
    __shared__ int rcur[RPB];
    const int b   = blockIdx.x;
    const int tid = threadIdx.x;

    if (tid < RPB) { cnt[tid] = 0; rcur[tid] = 0; }
    __syncthreads();

    const int beg = b * CAP;
    const int n   = min(bcnt[b], CAP);

    for (int i = tid; i < n; i += 256)
        atomicAdd(&cnt[(__float_as_int(bucket[beg + i].x) >> 16) & 127], 1);
    __syncthreads();

    if (tid < RPB) sc[tid] = cnt[tid];
    __syncthreads();
    #pragma unroll
    for (int off = 1; off < RPB; off <<= 1) {
        int a = 0;
        if (tid < RPB && tid >= off) a = sc[tid - off];
        __syncthreads();
        if (tid < RPB) sc[tid] += a;
        __syncthreads();
    }
    if (tid < RPB) {
        const int rb = beg + sc[tid] - cnt[tid];   // exclusive
        rbase[tid] = rb;
        rowOffs[b * 129 + tid] = rb;
    }
    if (tid == RPB) rowOffs[b * 129 + RPB] = beg + n;
    __syncthreads();

    for (int i = tid; i < n; i += 256) {
        const float2 ev  = bucket[beg + i];
        const int    key = __float_as_int(ev.x);
        const int    r   = (key >> 16) & 127;
        const int    pos = rbase[r] + atomicAdd(&rcur[r], 1);
        bucket2[pos] = make_float2(__int_as_float(key & 0xFFFF), ev.y);
    }
}

// ---------------------------------------------------------------------------
// Gather: thread = (row, f16), f16 in [0,6) -> 16 features. bf16 support.
// Register accumulate, fused ReLU, single write. No atomics.
// ---------------------------------------------------------------------------
__global__ __launch_bounds__(256) void k_gather(const int* __restrict__ rowOffs,
                                                const float2* __restrict__ bucket2,
                                                const unsigned short* __restrict__ support,
                                                float* __restrict__ out) {
    const int gid = blockIdx.x * 256 + threadIdx.x;
    if (gid >= N_NODES * 6) return;
    const int r   = gid / 6;
    const int f16 = gid - r * 6;

    const int idx = (r >> 7) * 129 + (r & 127);
    const int beg = rowOffs[idx];
    const int end = rowOffs[idx + 1];

    float acc[16];
    #pragma unroll
    for (int j = 0; j < 16; ++j) acc[j] = 0.f;

    for (int i = beg; i < end; ++i) {
        const float2 cv = bucket2[i];
        const int   c = __float_as_int(cv.x);
        const float v = cv.y;
        const unsigned short* sp = support + (size_t)c * F_OUT + f16 * 16;
        const bf16x8 s0 = *reinterpret_cast<const bf16x8*>(sp);
        const bf16x8 s1 = *reinterpret_cast<const bf16x8*>(sp + 8);
        #pragma unroll
        for (int j = 0; j < 8; ++j) {
            acc[j]     = fmaf(v, bf2f((unsigned short)s0[j]), acc[j]);
            acc[8 + j] = fmaf(v, bf2f((unsigned short)s1[j]), acc[8 + j]);
        }
    }

    float* o = out + (size_t)r * F_OUT + f16 * 16;
    #pragma unroll
    for (int q = 0; q < 4; ++q) {
        float4 ov;
        ov.x = fmaxf(acc[q * 4 + 0], 0.f);
        ov.y = fmaxf(acc[q * 4 + 1], 0.f);
        ov.z = fmaxf(acc[q * 4 + 2], 0.f);
        ov.w = fmaxf(acc[q * 4 + 3], 0.f);
        *reinterpret_cast<float4*>(o + q * 4) = ov;
    }
}

extern "C" void kernel_launch(void* const* d_in, const int* in_sizes, int n_in,
                              void* d_out, int out_size, void* d_ws, size_t ws_size,
                              hipStream_t stream) {
    const float* x    = (const float*)d_in[0];
    const int*   erow = (const int*)d_in[1];
    const int*   ecol = (const int*)d_in[2];
    const float* eval = (const float*)d_in[3];
    const float* w    = (const float*)d_in[4];
    float*       out  = (float*)d_out;

    // workspace layout (bytes from d_ws):
    unsigned short* support = (unsigned short*)d_ws;               // 9.6 MB
    int*    bcnt    = (int*)((char*)d_ws + 9600000);               // [391] pad 400
    int*    rowOffs = bcnt + 400;                                  // [50439] pad 50560
    unsigned short* wTq = (unsigned short*)(rowOffs + 50560);      // 49152 bf16
    float2* bucket  = (float2*)((char*)wTq + 98304);               // 8.0 MB
    float2* bucket2 = bucket + (size_t)NBKT * CAP;                 // 8.0 MB

    k_wcast<<<(F_OUT * F_IN + 255) / 256, 256, 0, stream>>>(w, wTq, bcnt);

    k_fused<<<NCHUNK + GEMM_BLOCKS, 256, 0, stream>>>(x, wTq, support,
                                                      erow, ecol, eval,
                                                      bcnt, bucket);

    kS_sort<<<NBKT, 256, 0, stream>>>(bcnt, bucket, bucket2, rowOffs);

    const int gthreads = N_NODES * 6;
    k_gather<<<(gthreads + 255) / 256, 256, 0, stream>>>(rowOffs, bucket2, support, out);
}